// Round 6
// baseline (170.254 us; speedup 1.0000x reference)
//
#include <hip/hip_runtime.h>
#include <cstdint>

// ---------------- problem constants ----------------
#define NIMG  16
#define NCLS  80
#define HH    100
#define WW    152
#define HWSZ  (HH*WW)          // 15200
#define HW4   (HWSZ/4)         // 3800
#define NE    (HWSZ*NCLS)      // 1216000
#define KTOP  1000
#define POSTN 100
#define PRE_T 0.05f
#define NMS_T 0.6f
#define FLOOR_KEY 0x3D000000u
#define FLOOR_BIN 976
#define CAND_CAP  8192
#define SEL_CAP   2048
#define MROWS 16               // NMS-mask rows per block
#define NTILE 240              // 64-elem chunk tiles per class (ceil(15200/64)=238, padded)
#define NCHUNK (NCLS*NTILE)    // 19200 chunks per image

// ---------------- workspace layout (bytes) ----------------
#define OFF_HIST1 972800u    // u32   [16][4096]
#define OFF_HIST2 1234944u   // u32   [16][4096]
#define OFF_META  1497088u   // u32   [16][16]  {0:thr1_bin,1:cumAbove1,2:cand_count,3:nvalid}
#define OFF_CAND  1498112u   // u64   [16][8192]
#define OFF_BOX   2546688u   // float [16][1000][4]
#define OFF_OBOX  2802688u   // float [16][1000][4]
#define OFF_SC    3058688u   // float [16][1000]
#define OFF_LAB   3122688u   // int   [16][1000]
#define OFF_MASK  3186688u   // u64   [16][1000][16]
// chunkmax overlaps BOX..MASK-head region: written by k_hist, dead after k_collect,
// while BOX/OBOX/SC/LAB/MASK are written only by k_select/k_mask (later). Safe.
#define OFF_CMAX  2546688u   // u32   [16][19200]  (1,228,800 B)
#define OFF_COLS  5234688u   // u64   [16][16][64] transposed diagonal blocks (131,072 B)
#define OFF_KEEP  5365760u   // u64   [16][16] keep bitmap

__device__ __forceinline__ float sigm(float x) { return 1.f / (1.f + expf(-x)); }

__device__ __forceinline__ uint64_t shfl64(uint64_t v, int src) {
  int lo = __shfl((int)(uint32_t)(v & 0xffffffffu), src, 64);
  int hi = __shfl((int)(uint32_t)(v >> 32), src, 64);
  return ((uint64_t)(uint32_t)hi << 32) | (uint32_t)lo;
}
__device__ __forceinline__ uint64_t shfl64x(uint64_t v, int d) {
  int lo = __shfl_xor((int)(uint32_t)(v & 0xffffffffu), d, 64);
  int hi = __shfl_xor((int)(uint32_t)(v >> 32), d, 64);
  return ((uint64_t)(uint32_t)hi << 32) | (uint32_t)lo;
}

// descending bitonic sort, thread-per-pair: one LDS round-trip per pass
__device__ __forceinline__ void bitonic_desc_tpp(uint64_t* s, int nn, int t, int nt) {
  const int np = nn >> 1;
  for (int k2 = 2; k2 <= nn; k2 <<= 1) {
    for (int j = k2 >> 1; j > 0; j >>= 1) {
      __syncthreads();
      for (int q = t; q < np; q += nt) {
        int i = ((q & ~(j - 1)) << 1) | (q & (j - 1));
        int p = i | j;
        uint64_t a = s[i], b = s[p];
        bool desc = ((i & k2) == 0);
        bool sw = desc ? (a < b) : (a > b);
        if (sw) { s[i] = b; s[p] = a; }
      }
    }
  }
  __syncthreads();
}

// ---------------- kernel 1: score histogram + per-chunk max keys ----------------
__global__ void k_hist(const float4* __restrict__ cls4, const float4* __restrict__ ctr4,
                       unsigned* __restrict__ hist1, unsigned* __restrict__ cmax) {
  __shared__ unsigned h[4096];
  const int n = blockIdx.y;
  const int z = blockIdx.z;
  const int t = threadIdx.x;
  for (int i = t; i < 4096; i += blockDim.x) h[i] = 0;
  __syncthreads();
  const int idx = blockIdx.x * blockDim.x + t;   // grid.x=15 -> 3840 >= 3800
  float ct0 = 0, ct1 = 0, ct2 = 0, ct3 = 0;
  if (idx < HW4) {
    const float4 c4 = ctr4[n * HW4 + idx];
    ct0 = sigm(c4.x); ct1 = sigm(c4.y); ct2 = sigm(c4.z); ct3 = sigm(c4.w);
  }
  const float4* cp = cls4 + (size_t)n * (NE / 4);
  const int tile = idx >> 4;
#pragma unroll 4
  for (int c = z * 16; c < z * 16 + 16; ++c) {
    unsigned k0 = 0, k1 = 0, k2 = 0, k3 = 0;
    if (idx < HW4) {
      float4 v = cp[c * HW4 + idx];
      float s0 = sigm(v.x), s1 = sigm(v.y), s2 = sigm(v.z), s3 = sigm(v.w);
      k0 = (s0 > PRE_T) ? __float_as_uint(s0 * ct0) : 0u;
      k1 = (s1 > PRE_T) ? __float_as_uint(s1 * ct1) : 0u;
      k2 = (s2 > PRE_T) ? __float_as_uint(s2 * ct2) : 0u;
      k3 = (s3 > PRE_T) ? __float_as_uint(s3 * ct3) : 0u;
      if (k0 >= FLOOR_KEY) atomicAdd(&h[k0 >> 20], 1u);
      if (k1 >= FLOOR_KEY) atomicAdd(&h[k1 >> 20], 1u);
      if (k2 >= FLOOR_KEY) atomicAdd(&h[k2 >> 20], 1u);
      if (k3 >= FLOOR_KEY) atomicAdd(&h[k3 >> 20], 1u);
    }
    unsigned km = max(max(k0, k1), max(k2, k3));
    km = max(km, (unsigned)__shfl_xor((int)km, 1, 64));
    km = max(km, (unsigned)__shfl_xor((int)km, 2, 64));
    km = max(km, (unsigned)__shfl_xor((int)km, 4, 64));
    km = max(km, (unsigned)__shfl_xor((int)km, 8, 64));
    if ((t & 15) == 0) cmax[(size_t)n * NCHUNK + c * NTILE + tile] = km;
  }
  __syncthreads();
  for (int i = t; i < 4096; i += blockDim.x) {
    unsigned v = h[i];
    if (v) atomicAdd(&hist1[n * 4096 + i], v);
  }
}

// ---------------- kernel 2: find level-1 threshold bin ----------------
__global__ void k_findbin(const unsigned* __restrict__ hist1, unsigned* __restrict__ meta) {
  const int n = blockIdx.x;
  __shared__ unsigned part[256];
  const unsigned* h = hist1 + n * 4096;
  const int t = threadIdx.x;
  unsigned ps = 0;
  for (int i = 0; i < 16; ++i) ps += h[t * 16 + i];
  part[t] = ps;
  __syncthreads();
  if (t == 0) {
    unsigned cum = 0, cumAbove = 0;
    int bin = -1;
    for (int ch = 255; ch >= 0 && bin < 0; --ch) {
      if (cum + part[ch] >= (unsigned)KTOP) {
        for (int i = 15; i >= 0; --i) {
          unsigned v = h[ch * 16 + i];
          if (cum + v >= (unsigned)KTOP) { bin = ch * 16 + i; cumAbove = cum; break; }
          cum += v;
        }
      } else cum += part[ch];
    }
    if (bin < 0) {            // fewer than KTOP candidates above floor: take all
      bin = FLOOR_BIN;
      cumAbove = cum - h[FLOOR_BIN];
    }
    meta[n * 16 + 0] = (unsigned)bin;
    meta[n * 16 + 1] = cumAbove;
  }
}

// ---------------- kernel 3: chunkmax-gated sparse collect ----------------
__global__ void k_collect(const float* __restrict__ cls, const float* __restrict__ ctr,
                          const unsigned* __restrict__ cmax,
                          unsigned* __restrict__ meta, unsigned* __restrict__ hist2,
                          uint64_t* __restrict__ cand) {
  const int n = blockIdx.y;
  const unsigned thr1 = meta[n * 16 + 0];
  const unsigned thrKey1 = thr1 << 20;
  const int lane = threadIdx.x & 63;
  const int cbase = (blockIdx.x * 4 + (threadIdx.x >> 6)) * 64;   // grid.x=75 -> 19200 chunks
  unsigned cm = cmax[(size_t)n * NCHUNK + cbase + lane];
  uint64_t hot = __ballot(cm >= thrKey1);
  while (hot) {
    int b = __ffsll((unsigned long long)hot) - 1;
    hot &= hot - 1;
    int hc = cbase + b;
    int c = hc / NTILE, tile = hc - c * NTILE;
    int hw = tile * 64 + lane;
    if (hw < HWSZ) {
      float s1 = sigm(cls[((size_t)n * NCLS + c) * HWSZ + hw]);
      float sc = sigm(ctr[(size_t)n * HWSZ + hw]);
      unsigned key = (s1 > PRE_T) ? __float_as_uint(s1 * sc) : 0u;
      if (key >= thrKey1) {
        unsigned fidx = (unsigned)(hw * NCLS + c);
        uint64_t comp = ((uint64_t)key << 21) | (uint64_t)(0x1FFFFFu - fidx);
        unsigned pos = atomicAdd(&meta[n * 16 + 2], 1u);
        if (pos < CAND_CAP) cand[(size_t)n * CAND_CAP + pos] = comp;
        if ((key >> 20) == thr1) atomicAdd(&hist2[n * 4096 + ((key >> 8) & 0xFFFu)], 1u);
      }
    }
  }
}

// ---------------- kernel 4: level-2 threshold, gather, sort, decode (1024 thr) ----------------
__global__ void __launch_bounds__(1024) k_select(
    const unsigned* __restrict__ hist2, unsigned* __restrict__ meta,
    const uint64_t* __restrict__ cand,
    const float* __restrict__ locations, const float* __restrict__ breg,
    const int* __restrict__ imsz,
    float* __restrict__ boxes, float* __restrict__ obox,
    float* __restrict__ scw, int* __restrict__ labw) {
  const int n = blockIdx.x;
  const int t = threadIdx.x;
  __shared__ uint64_t sel[SEL_CAP];
  __shared__ unsigned part[256];
  __shared__ int selcnt;
  __shared__ unsigned thrKey2s;
  const unsigned thr1 = meta[n * 16 + 0];
  const unsigned cumAbove = meta[n * 16 + 1];
  const int ccount = (int)min(meta[n * 16 + 2], (unsigned)CAND_CAP);
  const unsigned* h2 = hist2 + n * 4096;
  if (t < 256) {
    unsigned ps = 0;
    for (int i = 0; i < 16; ++i) ps += h2[t * 16 + i];
    part[t] = ps;
  }
  if (t == 0) selcnt = 0;
  __syncthreads();
  if (t == 0) {
    int need = (int)KTOP - (int)cumAbove;   // >= 1
    unsigned cum = 0;
    int b2 = -1;
    for (int ch = 255; ch >= 0 && b2 < 0; --ch) {
      if ((int)(cum + part[ch]) >= need) {
        for (int i = 15; i >= 0; --i) {
          unsigned v = h2[ch * 16 + i];
          if ((int)(cum + v) >= need) { b2 = ch * 16 + i; break; }
          cum += v;
        }
      } else cum += part[ch];
    }
    thrKey2s = (b2 < 0) ? (thr1 << 20) : ((thr1 << 20) | ((unsigned)b2 << 8));
  }
  __syncthreads();
  const unsigned thrKey2 = thrKey2s;
  for (int j = t; j < ccount; j += 1024) {
    uint64_t comp = cand[(size_t)n * CAND_CAP + j];
    unsigned key = (unsigned)(comp >> 21);
    if (key >= thrKey2) {
      int pos = atomicAdd(&selcnt, 1);
      if (pos < SEL_CAP) sel[pos] = comp;
    }
  }
  __syncthreads();
  const int m = min(selcnt, SEL_CAP);
  for (int j = t + m; j < SEL_CAP; j += 1024) sel[j] = 0;
  __syncthreads();
  bitonic_desc_tpp(sel, SEL_CAP, t, 1024);
  const int nv = min(m, KTOP);
  if (t == 0) meta[n * 16 + 3] = (unsigned)nv;
  const float hi = (float)imsz[n * 2 + 0];
  const float wi = (float)imsz[n * 2 + 1];
  const float offmul = fmaxf(wi, hi) + 1.0f;
  for (int k = t; k < KTOP; k += 1024) {
    float x1 = 0, y1 = 0, x2 = 0, y2 = 0, ox1 = 0, oy1 = 0, ox2 = 0, oy2 = 0, s = 0;
    int lab = 0;
    if (k < nv) {
      uint64_t comp = sel[k];
      unsigned key = (unsigned)(comp >> 21);
      unsigned idx = 0x1FFFFFu - (unsigned)(comp & 0x1FFFFFu);
      int hw = (int)(idx / NCLS);
      int c  = (int)(idx - (unsigned)hw * NCLS);
      lab = c + 1;
      float lx = locations[hw * 2 + 0];
      float ly = locations[hw * 2 + 1];
      const float* rg = breg + (size_t)n * 4 * HWSZ;
      float rl = rg[hw], rt = rg[HWSZ + hw], rr = rg[2 * HWSZ + hw], rb = rg[3 * HWSZ + hw];
      x1 = fminf(fmaxf(lx - rl, 0.f), wi - 1.f);
      x2 = fminf(fmaxf(lx + rr, 0.f), wi - 1.f);
      y1 = fminf(fmaxf(ly - rt, 0.f), hi - 1.f);
      y2 = fminf(fmaxf(ly + rb, 0.f), hi - 1.f);
      float off = (float)lab * offmul;
      asm volatile("" : "+v"(off));      // keep the rounded off, forbid fma fusion
      ox1 = x1 + off; oy1 = y1 + off; ox2 = x2 + off; oy2 = y2 + off;
      s = sqrtf(__uint_as_float(key));
    }
    size_t b = (size_t)(n * KTOP + k);
    boxes[b * 4 + 0] = x1; boxes[b * 4 + 1] = y1; boxes[b * 4 + 2] = x2; boxes[b * 4 + 3] = y2;
    obox[b * 4 + 0] = ox1; obox[b * 4 + 1] = oy1; obox[b * 4 + 2] = ox2; obox[b * 4 + 3] = oy2;
    scw[b] = s;
    labw[b] = lab;
  }
}

// ------ kernel 5: NMS adjacency bitmask + transposed diagonal columns (via symmetry) ------
__global__ void k_mask(const float* __restrict__ obox, const unsigned* __restrict__ meta,
                       uint64_t* __restrict__ masks, uint64_t* __restrict__ colsg) {
  const int n = blockIdx.y;
  const int r0 = blockIdx.x * MROWS;
  const int nv = (int)meta[n * 16 + 3];
  if (r0 >= nv) return;
  __shared__ float4 obs[KTOP];
  __shared__ float ars[KTOP];
  const int t = threadIdx.x;
  const float4* ob = (const float4*)obox + (size_t)n * KTOP;
  for (int j = t; j < KTOP; j += 256) {
    float4 b = ob[j];
    obs[j] = b;
    ars[j] = (b.z - b.x) * (b.w - b.y);   // LDS round-trip => rounded, no fusion across
  }
  __syncthreads();
  const int lane = t & 63;
  const int wv = t >> 6;
  for (int rr = wv; rr < MROWS; rr += 4) {
    const int r = r0 + rr;
    if (r >= nv) continue;                 // wave-uniform branch
    const float4 bi = obs[r];
    const float areai = ars[r];
    const int Wr = r >> 6;
    uint64_t* mr = masks + ((size_t)n * KTOP + r) * 16;
    for (int w = 0; w < 16; ++w) {
      int j = (w << 6) + lane;
      bool over = false;
      if (j < nv && j != r) {
        float4 bj = obs[j];
        float areaj = ars[j];
        float ltx = fmaxf(bi.x, bj.x), lty = fmaxf(bi.y, bj.y);
        float rbx = fminf(bi.z, bj.z), rby = fminf(bi.w, bj.w);
        float wx = fmaxf(rbx - ltx, 0.f), wy = fmaxf(rby - lty, 0.f);
        float inter = wx * wy;
        asm volatile("" : "+v"(inter));
        float denom = areai + areaj - inter + 1e-9f;
        over = (inter / denom) > NMS_T;
      }
      uint64_t bu = __ballot(over && (j > r));
      if (lane == 0) mr[w] = bu;
      if (w == Wr) {
        // column r of diagonal block: bit j = IoU(j,r)>T && j<r (symmetry)
        uint64_t bc = __ballot(over && (j < r));
        if (lane == 0) colsg[((size_t)n * 16 + w) * 64 + (r & 63)] = bc;
      }
    }
  }
}

// ---------------- kernel 6: ballot fixed-point greedy NMS scan -> keepbits ----------------
__global__ void __launch_bounds__(1024) k_scan(
    const uint64_t* __restrict__ masks, const uint64_t* __restrict__ colsg,
    const unsigned* __restrict__ meta, uint64_t* __restrict__ keep_g) {
  const int n = blockIdx.x;
  const int t = threadIdx.x;
  __shared__ uint64_t shmP[KTOP * 17];   // padded stride-17: 136,000 B
  const int nv = (int)meta[n * 16 + 3];
  const int lane = t & 63;
  // stage 1000x16 words, padded rows (stride 17)
  const ulonglong2* src = (const ulonglong2*)(masks + (size_t)n * KTOP * 16);
  for (int j2 = t; j2 < KTOP * 8; j2 += 1024) {
    ulonglong2 v = src[j2];
    int row = j2 >> 3, wp = (j2 & 7) << 1;
    shmP[row * 17 + wp] = v.x;
    shmP[row * 17 + wp + 1] = v.y;
  }
  __syncthreads();
  if (t < 64) {
    uint64_t colr[16];
#pragma unroll
    for (int W = 0; W < 16; ++W) colr[W] = colsg[((size_t)n * 16 + W) * 64 + lane];
    uint64_t rmv = 0;   // lanes 0..15: accumulated suppression words from kept rows
    const uint64_t below = (lane == 0) ? 0ull : (~0ull >> (64 - lane));
#pragma unroll
    for (int W = 0; W < 16; ++W) {
      const int lo = W << 6;
      uint64_t cur0 = shfl64(rmv, W);
      if (nv <= lo) cur0 = ~0ull;
      else if (nv < lo + 64) cur0 |= (~0ull) << (nv - lo);
      // ballot fixed point == greedy keep set of this 64-block
      uint64_t kept = ~cur0;
      for (int it = 0; it < 64; ++it) {
        bool pred = (((cur0 >> lane) & 1ull) == 0) && ((colr[W] & kept & below) == 0ull);
        uint64_t kn = __ballot(pred);
        if (kn == kept) break;
        kept = kn;
      }
      if (lane == 0) keep_g[n * 16 + W] = kept;
      // bulk-OR kept rows into rmv: lane = g*16+w handles rows i2*4+g, word w
      const int w = lane & 15, g = lane >> 4;
      uint64_t acc = 0;
#pragma unroll
      for (int i2 = 0; i2 < 16; ++i2) {
        const int i = (i2 << 2) + g;
        uint64_t msk = (uint64_t)0 - ((kept >> i) & 1ull);
        acc |= shmP[(lo + i) * 17 + w] & msk;
      }
      acc |= shfl64x(acc, 16);
      acc |= shfl64x(acc, 32);
      if (lane < 16) rmv |= acc;
    }
  }
}

// ---------------- kernel 7: gather kept, top-100 sort, write output ----------------
__global__ void __launch_bounds__(1024) k_out(
    const uint64_t* __restrict__ keep_g, const float* __restrict__ boxes,
    const float* __restrict__ scw, const int* __restrict__ labw,
    float* __restrict__ out) {
  const int n = blockIdx.x;
  const int t = threadIdx.x;
  __shared__ uint64_t sel[1024];
  __shared__ uint64_t kb[16];
  if (t < 16) kb[t] = keep_g[n * 16 + t];
  __syncthreads();
  {
    const int k = t;
    uint64_t comp = 0;
    if (k < KTOP && ((kb[k >> 6] >> (k & 63)) & 1ull)) {
      unsigned s = __float_as_uint(scw[(size_t)n * KTOP + k]);   // > 0 for kept
      comp = ((uint64_t)s << 10) | (uint64_t)(1023 - k);
    }
    sel[k] = comp;
  }
  __syncthreads();
  bitonic_desc_tpp(sel, 1024, t, 1024);
  if (t < POSTN) {
    const int k = t;
    uint64_t comp = sel[k];
    float x1 = 0, y1 = 0, x2 = 0, y2 = 0, fs = 0;
    int lab = 0;
    if (comp != 0) {
      int i = 1023 - (int)(comp & 0x3FFull);
      fs = __uint_as_float((unsigned)(comp >> 10));
      size_t b = (size_t)(n * KTOP + i);
      x1 = boxes[b * 4 + 0]; y1 = boxes[b * 4 + 1]; x2 = boxes[b * 4 + 2]; y2 = boxes[b * 4 + 3];
      lab = labw[b];
    }
    float* dr = out + (size_t)(n * POSTN + k) * 5;
    dr[0] = x1; dr[1] = y1; dr[2] = x2; dr[3] = y2; dr[4] = fs;
    out[(size_t)NIMG * POSTN * 5 + (size_t)n * POSTN + k] = (float)lab;
  }
}

extern "C" void kernel_launch(void* const* d_in, const int* in_sizes, int n_in,
                              void* d_out, int out_size, void* d_ws, size_t ws_size,
                              hipStream_t stream) {
  const float* locations = (const float*)d_in[0];
  const float* box_cls = (const float*)d_in[1];
  const float* box_reg = (const float*)d_in[2];
  const float* centerness = (const float*)d_in[3];
  const int* image_sizes = (const int*)d_in[4];
  char* ws = (char*)d_ws;

  unsigned* hist1 = (unsigned*)(ws + OFF_HIST1);
  unsigned* hist2 = (unsigned*)(ws + OFF_HIST2);
  unsigned* meta = (unsigned*)(ws + OFF_META);
  uint64_t* cand = (uint64_t*)(ws + OFF_CAND);
  float* boxes = (float*)(ws + OFF_BOX);
  float* obox = (float*)(ws + OFF_OBOX);
  float* scw = (float*)(ws + OFF_SC);
  int* labw = (int*)(ws + OFF_LAB);
  uint64_t* masks = (uint64_t*)(ws + OFF_MASK);
  unsigned* cmaxp = (unsigned*)(ws + OFF_CMAX);
  uint64_t* colsg = (uint64_t*)(ws + OFF_COLS);
  uint64_t* keep_g = (uint64_t*)(ws + OFF_KEEP);
  float* out = (float*)d_out;

  // zero hist1+hist2+meta (contiguous); ws is poisoned once, not re-zeroed between replays
  hipMemsetAsync(ws + OFF_HIST1, 0, (OFF_META + 1024) - OFF_HIST1, stream);

  k_hist<<<dim3(15, NIMG, 5), 256, 0, stream>>>((const float4*)box_cls,
                                                (const float4*)centerness, hist1, cmaxp);
  k_findbin<<<NIMG, 256, 0, stream>>>(hist1, meta);
  k_collect<<<dim3(75, NIMG), 256, 0, stream>>>(box_cls, centerness, cmaxp,
                                                meta, hist2, cand);
  k_select<<<NIMG, 1024, 0, stream>>>(hist2, meta, cand, locations, box_reg, image_sizes,
                                      boxes, obox, scw, labw);
  k_mask<<<dim3((KTOP + MROWS - 1) / MROWS, NIMG), 256, 0, stream>>>(obox, meta, masks, colsg);
  k_scan<<<NIMG, 1024, 0, stream>>>(masks, colsg, meta, keep_g);
  k_out<<<NIMG, 1024, 0, stream>>>(keep_g, boxes, scw, labw, out);
}